// Round 11
// baseline (174.729 us; speedup 1.0000x reference)
//
#include <hip/hip_runtime.h>

// Fused axial dual-branch attention, bf16 split-precision MFMA. One block per N.
// R11 = R10 + PT pad removed via XOR unit-swizzle -> LDS 30976 B -> 5 blocks/CU.
// PT: 128 t-rows x 64 s-cols, stride 64 u16; 8-byte units swizzled u' = u ^ (2*(t&7))
// (even xor keeps 16B read pairs adjacent+aligned; gram uint2 write = exactly 1 unit).
// Wave w: gram s-tile [64h+16w,+16) -> PT half-image; PV t-chunk [32w,+32), K=64/half.
// Q GEMM 3-term hi/lo split; V single-term bf16; exp2 softmax w/ scale folded into Wq.
// Frags (HW-verified): A[m=lane&15][k=quad*8+j]; B[k=quad*8+j][n=lane&15];
// D row=(lane>>4)*4+reg, col=lane&15.
// Lessons: R5vsR8 occupancy dominates barriers; R10 VALU cuts sub-linear (latency-bound).

typedef __attribute__((ext_vector_type(8))) short bh8;
typedef __attribute__((ext_vector_type(4))) float f32x4;
typedef unsigned short u16;
typedef unsigned int u32;

#define MFMA16(a,b,c) __builtin_amdgcn_mfma_f32_16x16x32_bf16(a,b,c,0,0,0)

#define AIMG_ST 72    // u16 (144 B rows)
#define QP_ST   40    // u16 (80 B rows)
#define VH_ST   136   // u16 (272 B rows)
#define PT_ST   64    // u16 (128 B rows, XOR-swizzled 8B units, no pad)

#define OFF_AH   0
#define OFF_AL   4608
#define OFF_VIN  9216
#define OFF_PT   0        // PT (128x64x2=16384) aliases Ah/Al/VIN (disjoint lifetimes)
#define OFF_QP   16384    // 128x40x2 = 10240
#define OFF_VH   26624    // 16x136x2 = 4352
#define LDS_TOT  30976    // x5 blocks = 151.25 KB <= 160 KB -> 5 blocks/CU

// ---- fast numeric helpers (guarded HW builtins, safe fallbacks) ----
__device__ __forceinline__ u32 cvtpk_rn(float f0, float f1) {
#if __has_builtin(__builtin_amdgcn_cvt_pk_bf16_f32)
    auto h = __builtin_amdgcn_cvt_pk_bf16_f32(f0, f1);
    u32 r; __builtin_memcpy(&r, &h, sizeof(r)); return r;
#else
    return ((__float_as_uint(f0) + 0x8000u) >> 16) |
           ((__float_as_uint(f1) + 0x8000u) & 0xFFFF0000u);
#endif
}
__device__ __forceinline__ float fexp2(float x) {
#if __has_builtin(__builtin_amdgcn_exp2f)
    return __builtin_amdgcn_exp2f(x);
#else
    return exp2f(x);
#endif
}
__device__ __forceinline__ float frcp(float x) {
#if __has_builtin(__builtin_amdgcn_rcpf)
    return __builtin_amdgcn_rcpf(x);
#else
    return 1.0f / x;
#endif
}
// hi = trunc-bf16 pair (1 v_perm), lo = RN-bf16(residual) pair
__device__ __forceinline__ void splitpk(float f0, float f1, u32& hp, u32& lp) {
    u32 u0 = __float_as_uint(f0), u1 = __float_as_uint(f1);
    hp = __builtin_amdgcn_perm(u1, u0, 0x07060302u);   // [u0.hi16 | u1.hi16]
    float r0 = f0 - __uint_as_float(u0 & 0xFFFF0000u);
    float r1 = f1 - __uint_as_float(u1 & 0xFFFF0000u);
    lp = cvtpk_rn(r0, r1);
}
__device__ __forceinline__ void split3(float f, u16& h, u16& l) {
    u32 u = __float_as_uint(f);
    u32 hf = u & 0xFFFF0000u;
    float r = f - __uint_as_float(hf);
    h = (u16)(hf >> 16);
    l = (u16)((__float_as_uint(r) + 0x8000u) >> 16);
}
__device__ __forceinline__ u16 rnbf(float f) {
    return (u16)((__float_as_uint(f) + 0x8000u) >> 16);
}
__device__ __forceinline__ float lrelu(float x) { return x > 0.f ? x : 0.2f * x; }

// ws u16 layout: [WqH 4096][WqL 4096][WkH 4096][WkL 4096 (unused)]
// Wq pre-scaled by 0.5*sqrt(log2 e) so Gram is natively log2e-scaled for exp2.
__global__ void split_w_kernel(const float* __restrict__ Wq,
                               const float* __restrict__ Wk,
                               u16* __restrict__ ws)
{
    const int i = blockIdx.x * 256 + threadIdx.x;
    const int j = i & 4095;
    const float scale = (i < 4096) ? 0.6005612043932249f : 1.0f;
    const float f = ((i < 4096) ? Wq[j] : Wk[j]) * scale;
    const int base = (i < 4096) ? 0 : 8192;
    u16 h, l; split3(f, h, l);
    ws[base + j] = h;
    ws[base + 4096 + j] = l;
}

#define WOFF(n, ks) (((n)*16 + lid)*64 + (ks)*32 + quad*8)

// Q GEMM: 3-term hi/lo split, 12 MFMA (scale pre-folded into weights), -> Qpack.
__device__ __forceinline__ void gemm_q(const u16* Ah, const u16* Al,
                                       const u16* wsu,
                                       u16* qp, int miQ, int niA, int lid, int quad)
{
    const bh8 h0a = *(const bh8*)(wsu +        WOFF(niA+0,0));
    const bh8 h0b = *(const bh8*)(wsu +        WOFF(niA+0,1));
    const bh8 h1a = *(const bh8*)(wsu +        WOFF(niA+1,0));
    const bh8 h1b = *(const bh8*)(wsu +        WOFF(niA+1,1));
    const bh8 l0a = *(const bh8*)(wsu + 4096 + WOFF(niA+0,0));
    const bh8 l0b = *(const bh8*)(wsu + 4096 + WOFF(niA+0,1));
    const bh8 l1a = *(const bh8*)(wsu + 4096 + WOFF(niA+1,0));
    const bh8 l1b = *(const bh8*)(wsu + 4096 + WOFF(niA+1,1));
    const int offA = (miQ*16 + lid)*AIMG_ST + quad*8;
    bh8 ah0 = *(const bh8*)(Ah + offA);
    bh8 ah1 = *(const bh8*)(Ah + offA + 32);
    bh8 al0 = *(const bh8*)(Al + offA);
    bh8 al1 = *(const bh8*)(Al + offA + 32);
    f32x4 acc0 = {0.f,0.f,0.f,0.f}, acc1 = {0.f,0.f,0.f,0.f};
    acc0 = MFMA16(ah0, h0a, acc0); acc0 = MFMA16(ah0, l0a, acc0); acc0 = MFMA16(al0, h0a, acc0);
    acc0 = MFMA16(ah1, h0b, acc0); acc0 = MFMA16(ah1, l0b, acc0); acc0 = MFMA16(al1, h0b, acc0);
    acc1 = MFMA16(ah0, h1a, acc1); acc1 = MFMA16(ah0, l1a, acc1); acc1 = MFMA16(al0, h1a, acc1);
    acc1 = MFMA16(ah1, h1b, acc1); acc1 = MFMA16(ah1, l1b, acc1); acc1 = MFMA16(al1, h1b, acc1);
    #pragma unroll
    for (int r = 0; r < 4; ++r) {
        const int l = miQ*16 + quad*4 + r;
        const int d = l >> 1;
        const int sbase = (l & 1) << 6;
        const int s0 = sbase + (niA + 0)*16 + lid;
        const int s1 = sbase + (niA + 1)*16 + lid;
        u32 hp, lp;
        splitpk(acc0[r], acc1[r], hp, lp);
        qp[s0*QP_ST + d]      = (u16)hp;
        qp[s0*QP_ST + 16 + d] = (u16)lp;
        qp[s1*QP_ST + d]      = (u16)(hp >> 16);
        qp[s1*QP_ST + 16 + d] = (u16)(lp >> 16);
    }
}

// V GEMM: single-term bf16, 4 MFMA, writes VH[d][s].
__device__ __forceinline__ void gemm_v(const u16* Vin, const u16* wsu,
                                       u16* vh, int miQ, int niA, int lid, int quad)
{
    const bh8 h0a = *(const bh8*)(wsu + 8192 + WOFF(niA+0,0));
    const bh8 h0b = *(const bh8*)(wsu + 8192 + WOFF(niA+0,1));
    const bh8 h1a = *(const bh8*)(wsu + 8192 + WOFF(niA+1,0));
    const bh8 h1b = *(const bh8*)(wsu + 8192 + WOFF(niA+1,1));
    const int offA = (miQ*16 + lid)*AIMG_ST + quad*8;
    bh8 ah0 = *(const bh8*)(Vin + offA);
    bh8 ah1 = *(const bh8*)(Vin + offA + 32);
    f32x4 acc0 = {0.f,0.f,0.f,0.f}, acc1 = {0.f,0.f,0.f,0.f};
    acc0 = MFMA16(ah0, h0a, acc0); acc0 = MFMA16(ah1, h0b, acc0);
    acc1 = MFMA16(ah0, h1a, acc1); acc1 = MFMA16(ah1, h1b, acc1);
    #pragma unroll
    for (int r = 0; r < 4; ++r) {
        const int l = miQ*16 + quad*4 + r;
        const int d = l >> 1;
        const int sbase = (l & 1) << 6;
        vh[d*VH_ST + sbase + (niA + 0)*16 + lid] = rnbf(acc0[r]);
        vh[d*VH_ST + sbase + (niA + 1)*16 + lid] = rnbf(acc1[r]);
    }
}

// Gram + wave-local softmax (exp2, scale pre-folded) for s-tile [64h+16w, +16).
// P^T write: one 8B unit per (lane,ti), unit index (4w+quad) ^ (2*(t&7)), t&7==lid&7.
__device__ __forceinline__ void gram_pt(const u16* Qp, u16* PT, int h,
                                        int w, int lid, int quad)
{
    const u16* arow = Qp + (h*64 + 16*w + lid)*QP_ST;
    bh8 a1 = *(const bh8*)(arow + quad*8);                        // [Qh;Ql]
    bh8 t  = *(const bh8*)(arow + ((quad >= 2) ? (quad-2)*8 : 0));
    bh8 zz = t ^ t;
    bh8 a2 = (quad < 2) ? zz : t;                                 // [0;Qh]
    f32x4 g[8];
    #pragma unroll
    for (int ti = 0; ti < 8; ++ti) {
        const u16* brow = Qp + (ti*16 + lid)*QP_ST;
        bh8 b1 = *(const bh8*)(brow + (quad & 1)*8);              // [Qh;Qh]
        bh8 b2 = *(const bh8*)(brow + quad*8);                    // [Qh;Ql]
        f32x4 acc = {0.f,0.f,0.f,0.f};
        acc = MFMA16(a1, b1, acc);
        acc = MFMA16(a2, b2, acc);
        g[ti] = acc;
    }
    float inv[4];
    #pragma unroll
    for (int r = 0; r < 4; ++r) {
        float s = 0.f;
        #pragma unroll
        for (int ti = 0; ti < 8; ++ti) {
            const float p = fexp2(g[ti][r]);
            g[ti][r] = p; s += p;
        }
        s += __shfl_xor(s, 1); s += __shfl_xor(s, 2);
        s += __shfl_xor(s, 4); s += __shfl_xor(s, 8);
        inv[r] = frcp(s);
    }
    const int X  = 2*(lid & 7);           // row-dependent unit swizzle
    const int uc = ((4*w + quad) ^ X) << 2;   // u16 offset of this lane's 8B unit
    #pragma unroll
    for (int ti = 0; ti < 8; ++ti) {
        uint2 dv;
        dv.x = cvtpk_rn(g[ti][0]*inv[0], g[ti][1]*inv[1]);
        dv.y = cvtpk_rn(g[ti][2]*inv[2], g[ti][3]*inv[3]);
        *(uint2*)(PT + (ti*16 + lid)*PT_ST + uc) = dv;
    }
}

// PV for t-chunk [32w,+32), K=64 (s-half h), accumulating into c0,c1.
// P^T read: 16B = unit pair {(8ks+2quad)^X, +1} (X even -> adjacent & aligned).
__device__ __forceinline__ void pv_ctx(const u16* PT, const u16* Vh, int h,
                                       f32x4& c0, f32x4& c1, int w, int lid, int quad)
{
    const int X = 2*(lid & 7);
    #pragma unroll
    for (int tj2 = 0; tj2 < 2; ++tj2) {
        const int tj = 2*w + tj2;
        f32x4 acc = tj2 ? c1 : c0;
        #pragma unroll
        for (int ks = 0; ks < 2; ++ks) {
            bh8 pa = *(const bh8*)(PT + (tj*16 + lid)*PT_ST + (((8*ks + 2*quad) ^ X) << 2));
            bh8 vb = *(const bh8*)(Vh + lid*VH_ST + h*64 + ks*32 + quad*8);
            acc = MFMA16(pa, vb, acc);
        }
        if (tj2) c1 = acc; else c0 = acc;
    }
}

__global__ __launch_bounds__(256, 5)
void axial_attn_mfma(const float* __restrict__ z, const u16* __restrict__ wsu,
                     float* __restrict__ out)
{
    __shared__ __align__(16) unsigned char lds[LDS_TOT];
    u16* const ptAh = (u16*)(lds + OFF_AH);
    u16* const ptAl = (u16*)(lds + OFF_AL);
    u16* const ptPT = (u16*)(lds + OFF_PT);
    u16* const ptVI = (u16*)(lds + OFF_VIN);
    u16* const ptQP = (u16*)(lds + OFF_QP);
    u16* const ptVH = (u16*)(lds + OFF_VH);

    const int tid = threadIdx.x;
    const int w = tid >> 6, lane = tid & 63, quad = lane >> 4, lid = lane & 15;

    // XCD-aware swizzle: same-XCD blocks cover contiguous xi
    const int blk = blockIdx.x;
    const int j   = blk >> 3;
    const int xi  = ((blk & 7) << 4) | (j & 15);
    const int q   = (j >> 4) & 3;
    const int bi  = j >> 6;
    const int N   = (((bi << 7) | xi) << 2) | q;
    const size_t zbase = (size_t)bi << 20;

    const int c8 = tid >> 5, l5 = tid & 31;        // ch-octet, A-row
    const int vl0 = tid >> 4, vc0 = (tid & 15) << 2;
    const int miQ = w >> 1, niA = (w & 1) * 2;

    // ---- register prefetch of ALL z reads (thread owns 8 consecutive ch) ----
    float a1r[8], a2r[8];
    float4 v4[2];
    {
        const float* s1 = z + zbase + ((size_t)xi << 7) + (q << 5) + l5;
        const float* s2 = z + zbase + (((size_t)(q*32 + l5)) << 7) + xi;
        #pragma unroll
        for (int k = 0; k < 8; ++k)
            a1r[k] = s1[(size_t)(c8*8 + k) << 14];
        const float4* sv = (const float4*)(z + ((size_t)N << 11));
        v4[0] = sv[tid]; v4[1] = sv[tid + 256];
        #pragma unroll
        for (int k = 0; k < 8; ++k)
            a2r[k] = s2[(size_t)(c8*8 + k) << 14];
    }

    // ---- stage A1 (hi/lo, single b128 each) + Vin (RN pair-pack) ----
    {
        u32 hp[4], lp[4];
        #pragma unroll
        for (int k = 0; k < 4; ++k) splitpk(a1r[2*k], a1r[2*k+1], hp[k], lp[k]);
        *(uint4*)(ptAh + l5*AIMG_ST + c8*8) = make_uint4(hp[0], hp[1], hp[2], hp[3]);
        *(uint4*)(ptAl + l5*AIMG_ST + c8*8) = make_uint4(lp[0], lp[1], lp[2], lp[3]);
    }
    #pragma unroll
    for (int k = 0; k < 2; ++k) {
        const float4 vv = v4[k];
        uint2 dv;
        dv.x = cvtpk_rn(vv.x, vv.y);
        dv.y = cvtpk_rn(vv.z, vv.w);
        *(uint2*)(ptVI + (vl0 + 16*k)*AIMG_ST + vc0) = dv;
    }
    __syncthreads();                                            // S1

    gemm_q(ptAh, ptAl, wsu, ptQP, miQ, niA, lid, quad);         // Q1
    gemm_v(ptVI, wsu, ptVH, miQ, niA, lid, quad);               // V
    __syncthreads();                                            // S2

    f32x4 c10 = {0.f,0.f,0.f,0.f}, c11 = {0.f,0.f,0.f,0.f};
    gram_pt(ptQP, ptPT, 0, w, lid, quad);                       // branch-1 s-half 0
    __syncthreads();                                            // S3
    pv_ctx(ptPT, ptVH, 0, c10, c11, w, lid, quad);
    __syncthreads();                                            // S4 (WAR on PT)
    gram_pt(ptQP, ptPT, 1, w, lid, quad);                       // branch-1 s-half 1
    __syncthreads();                                            // S5
    pv_ctx(ptPT, ptVH, 1, c10, c11, w, lid, quad);
    __syncthreads();                                            // S6 (PT reads done)

    // ---- stage A2 (hi/lo, b128) into PT region ----
    {
        u32 hp[4], lp[4];
        #pragma unroll
        for (int k = 0; k < 4; ++k) splitpk(a2r[2*k], a2r[2*k+1], hp[k], lp[k]);
        *(uint4*)(ptAh + l5*AIMG_ST + c8*8) = make_uint4(hp[0], hp[1], hp[2], hp[3]);
        *(uint4*)(ptAl + l5*AIMG_ST + c8*8) = make_uint4(lp[0], lp[1], lp[2], lp[3]);
    }
    __syncthreads();                                            // S7

    gemm_q(ptAh, ptAl, wsu, ptQP, miQ, niA, lid, quad);         // Q2
    __syncthreads();                                            // S8

    f32x4 c20 = {0.f,0.f,0.f,0.f}, c21 = {0.f,0.f,0.f,0.f};
    gram_pt(ptQP, ptPT, 0, w, lid, quad);                       // branch-2 s-half 0
    __syncthreads();                                            // S9
    pv_ctx(ptPT, ptVH, 0, c20, c21, w, lid, quad);
    __syncthreads();                                            // S10 (WAR on PT)
    gram_pt(ptQP, ptPT, 1, w, lid, quad);                       // branch-2 s-half 1
    __syncthreads();                                            // S11
    pv_ctx(ptPT, ptVH, 1, c20, c21, w, lid, quad);

    // ---- epilogue: out[d=lid][t] = lrelu(ctx1)+lrelu(ctx2), float4 over r ----
    float* ob = out + ((size_t)N << 11) + lid*128;
    #pragma unroll
    for (int tj2 = 0; tj2 < 2; ++tj2) {
        f32x4 a = tj2 ? c11 : c10;
        f32x4 b = tj2 ? c21 : c20;
        float4 ov;
        ov.x = lrelu(a[0]) + lrelu(b[0]);
        ov.y = lrelu(a[1]) + lrelu(b[1]);
        ov.z = lrelu(a[2]) + lrelu(b[2]);
        ov.w = lrelu(a[3]) + lrelu(b[3]);
        *(float4*)(ob + (2*w + tj2)*16 + quad*4) = ov;
    }
}

extern "C" void kernel_launch(void* const* d_in, const int* in_sizes, int n_in,
                              void* d_out, int out_size, void* d_ws, size_t ws_size,
                              hipStream_t stream) {
    const float* z  = (const float*)d_in[0];
    const float* Wq = (const float*)d_in[1];
    const float* Wk = (const float*)d_in[2];
    float* out = (float*)d_out;
    u16* ws = (u16*)d_ws;
    hipLaunchKernelGGL(split_w_kernel, dim3(32), dim3(256), 0, stream, Wq, Wk, ws);
    hipLaunchKernelGGL(axial_attn_mfma, dim3(4096), dim3(256), 0, stream, z, ws, out);
}

// Round 12
// 155.406 us; speedup vs baseline: 1.1243x; 1.1243x over previous
//
#include <hip/hip_runtime.h>

// Fused axial dual-branch attention, bf16 split-precision MFMA. One block per N.
// R12 = R11 (PT XOR-swizzle, LDS 30976 B -> 5 blocks/CU possible) but with
// __launch_bounds__(256,4): R11's (256,5) made the allocator clamp to 48 VGPR ->
// scratch spills (+61MB WRITE, +29MB FETCH) that swamped the occupancy win.
// With min=4 the compiler picks ~64 VGPR (R9/R10 evidence); 64*5=320<=512 so the
// HW still reaches 5 blocks/CU via the LDS limit — occupancy WITHOUT spills.
// PT: 128 t x 64 s, stride 64 u16; 8B units swizzled u' = u ^ (2*(t&7)).
// Wave w: gram s-tile [64h+16w,+16) -> PT half; PV t-chunk [32w,+32), K=64/half.
// Q GEMM 3-term hi/lo split; V single-term bf16; exp2 softmax, scale folded into Wq.
// Frags (HW-verified): A[m=lane&15][k=quad*8+j]; B[k=quad*8+j][n=lane&15];
// D row=(lane>>4)*4+reg, col=lane&15.
// Lessons: R5vsR8 occupancy>barriers; R6/R11 never over-constrain the allocator.

typedef __attribute__((ext_vector_type(8))) short bh8;
typedef __attribute__((ext_vector_type(4))) float f32x4;
typedef unsigned short u16;
typedef unsigned int u32;

#define MFMA16(a,b,c) __builtin_amdgcn_mfma_f32_16x16x32_bf16(a,b,c,0,0,0)

#define AIMG_ST 72    // u16 (144 B rows)
#define QP_ST   40    // u16 (80 B rows)
#define VH_ST   136   // u16 (272 B rows)
#define PT_ST   64    // u16 (128 B rows, XOR-swizzled 8B units, no pad)

#define OFF_AH   0
#define OFF_AL   4608
#define OFF_VIN  9216
#define OFF_PT   0        // PT (128x64x2=16384) aliases Ah/Al/VIN (disjoint lifetimes)
#define OFF_QP   16384    // 128x40x2 = 10240
#define OFF_VH   26624    // 16x136x2 = 4352
#define LDS_TOT  30976    // x5 blocks = 151.25 KB <= 160 KB -> 5 blocks/CU (LDS-limited)

// ---- fast numeric helpers (guarded HW builtins, safe fallbacks) ----
__device__ __forceinline__ u32 cvtpk_rn(float f0, float f1) {
#if __has_builtin(__builtin_amdgcn_cvt_pk_bf16_f32)
    auto h = __builtin_amdgcn_cvt_pk_bf16_f32(f0, f1);
    u32 r; __builtin_memcpy(&r, &h, sizeof(r)); return r;
#else
    return ((__float_as_uint(f0) + 0x8000u) >> 16) |
           ((__float_as_uint(f1) + 0x8000u) & 0xFFFF0000u);
#endif
}
__device__ __forceinline__ float fexp2(float x) {
#if __has_builtin(__builtin_amdgcn_exp2f)
    return __builtin_amdgcn_exp2f(x);
#else
    return exp2f(x);
#endif
}
__device__ __forceinline__ float frcp(float x) {
#if __has_builtin(__builtin_amdgcn_rcpf)
    return __builtin_amdgcn_rcpf(x);
#else
    return 1.0f / x;
#endif
}
// hi = trunc-bf16 pair (1 v_perm), lo = RN-bf16(residual) pair
__device__ __forceinline__ void splitpk(float f0, float f1, u32& hp, u32& lp) {
    u32 u0 = __float_as_uint(f0), u1 = __float_as_uint(f1);
    hp = __builtin_amdgcn_perm(u1, u0, 0x07060302u);   // [u0.hi16 | u1.hi16]
    float r0 = f0 - __uint_as_float(u0 & 0xFFFF0000u);
    float r1 = f1 - __uint_as_float(u1 & 0xFFFF0000u);
    lp = cvtpk_rn(r0, r1);
}
__device__ __forceinline__ void split3(float f, u16& h, u16& l) {
    u32 u = __float_as_uint(f);
    u32 hf = u & 0xFFFF0000u;
    float r = f - __uint_as_float(hf);
    h = (u16)(hf >> 16);
    l = (u16)((__float_as_uint(r) + 0x8000u) >> 16);
}
__device__ __forceinline__ u16 rnbf(float f) {
    return (u16)((__float_as_uint(f) + 0x8000u) >> 16);
}
__device__ __forceinline__ float lrelu(float x) { return x > 0.f ? x : 0.2f * x; }

// ws u16 layout: [WqH 4096][WqL 4096][WkH 4096][WkL 4096 (unused)]
// Wq pre-scaled by 0.5*sqrt(log2 e) so Gram is natively log2e-scaled for exp2.
__global__ void split_w_kernel(const float* __restrict__ Wq,
                               const float* __restrict__ Wk,
                               u16* __restrict__ ws)
{
    const int i = blockIdx.x * 256 + threadIdx.x;
    const int j = i & 4095;
    const float scale = (i < 4096) ? 0.6005612043932249f : 1.0f;
    const float f = ((i < 4096) ? Wq[j] : Wk[j]) * scale;
    const int base = (i < 4096) ? 0 : 8192;
    u16 h, l; split3(f, h, l);
    ws[base + j] = h;
    ws[base + 4096 + j] = l;
}

#define WOFF(n, ks) (((n)*16 + lid)*64 + (ks)*32 + quad*8)

// Q GEMM: 3-term hi/lo split, 12 MFMA (scale pre-folded into weights), -> Qpack.
__device__ __forceinline__ void gemm_q(const u16* Ah, const u16* Al,
                                       const u16* wsu,
                                       u16* qp, int miQ, int niA, int lid, int quad)
{
    const bh8 h0a = *(const bh8*)(wsu +        WOFF(niA+0,0));
    const bh8 h0b = *(const bh8*)(wsu +        WOFF(niA+0,1));
    const bh8 h1a = *(const bh8*)(wsu +        WOFF(niA+1,0));
    const bh8 h1b = *(const bh8*)(wsu +        WOFF(niA+1,1));
    const bh8 l0a = *(const bh8*)(wsu + 4096 + WOFF(niA+0,0));
    const bh8 l0b = *(const bh8*)(wsu + 4096 + WOFF(niA+0,1));
    const bh8 l1a = *(const bh8*)(wsu + 4096 + WOFF(niA+1,0));
    const bh8 l1b = *(const bh8*)(wsu + 4096 + WOFF(niA+1,1));
    const int offA = (miQ*16 + lid)*AIMG_ST + quad*8;
    bh8 ah0 = *(const bh8*)(Ah + offA);
    bh8 ah1 = *(const bh8*)(Ah + offA + 32);
    bh8 al0 = *(const bh8*)(Al + offA);
    bh8 al1 = *(const bh8*)(Al + offA + 32);
    f32x4 acc0 = {0.f,0.f,0.f,0.f}, acc1 = {0.f,0.f,0.f,0.f};
    acc0 = MFMA16(ah0, h0a, acc0); acc0 = MFMA16(ah0, l0a, acc0); acc0 = MFMA16(al0, h0a, acc0);
    acc0 = MFMA16(ah1, h0b, acc0); acc0 = MFMA16(ah1, l0b, acc0); acc0 = MFMA16(al1, h0b, acc0);
    acc1 = MFMA16(ah0, h1a, acc1); acc1 = MFMA16(ah0, l1a, acc1); acc1 = MFMA16(al0, h1a, acc1);
    acc1 = MFMA16(ah1, h1b, acc1); acc1 = MFMA16(ah1, l1b, acc1); acc1 = MFMA16(al1, h1b, acc1);
    #pragma unroll
    for (int r = 0; r < 4; ++r) {
        const int l = miQ*16 + quad*4 + r;
        const int d = l >> 1;
        const int sbase = (l & 1) << 6;
        const int s0 = sbase + (niA + 0)*16 + lid;
        const int s1 = sbase + (niA + 1)*16 + lid;
        u32 hp, lp;
        splitpk(acc0[r], acc1[r], hp, lp);
        qp[s0*QP_ST + d]      = (u16)hp;
        qp[s0*QP_ST + 16 + d] = (u16)lp;
        qp[s1*QP_ST + d]      = (u16)(hp >> 16);
        qp[s1*QP_ST + 16 + d] = (u16)(lp >> 16);
    }
}

// V GEMM: single-term bf16, 4 MFMA, writes VH[d][s].
__device__ __forceinline__ void gemm_v(const u16* Vin, const u16* wsu,
                                       u16* vh, int miQ, int niA, int lid, int quad)
{
    const bh8 h0a = *(const bh8*)(wsu + 8192 + WOFF(niA+0,0));
    const bh8 h0b = *(const bh8*)(wsu + 8192 + WOFF(niA+0,1));
    const bh8 h1a = *(const bh8*)(wsu + 8192 + WOFF(niA+1,0));
    const bh8 h1b = *(const bh8*)(wsu + 8192 + WOFF(niA+1,1));
    const int offA = (miQ*16 + lid)*AIMG_ST + quad*8;
    bh8 ah0 = *(const bh8*)(Vin + offA);
    bh8 ah1 = *(const bh8*)(Vin + offA + 32);
    f32x4 acc0 = {0.f,0.f,0.f,0.f}, acc1 = {0.f,0.f,0.f,0.f};
    acc0 = MFMA16(ah0, h0a, acc0); acc0 = MFMA16(ah1, h0b, acc0);
    acc1 = MFMA16(ah0, h1a, acc1); acc1 = MFMA16(ah1, h1b, acc1);
    #pragma unroll
    for (int r = 0; r < 4; ++r) {
        const int l = miQ*16 + quad*4 + r;
        const int d = l >> 1;
        const int sbase = (l & 1) << 6;
        vh[d*VH_ST + sbase + (niA + 0)*16 + lid] = rnbf(acc0[r]);
        vh[d*VH_ST + sbase + (niA + 1)*16 + lid] = rnbf(acc1[r]);
    }
}

// Gram + wave-local softmax (exp2, scale pre-folded) for s-tile [64h+16w, +16).
// P^T write: one 8B unit per (lane,ti), unit index (4w+quad) ^ (2*(t&7)), t&7==lid&7.
__device__ __forceinline__ void gram_pt(const u16* Qp, u16* PT, int h,
                                        int w, int lid, int quad)
{
    const u16* arow = Qp + (h*64 + 16*w + lid)*QP_ST;
    bh8 a1 = *(const bh8*)(arow + quad*8);                        // [Qh;Ql]
    bh8 t  = *(const bh8*)(arow + ((quad >= 2) ? (quad-2)*8 : 0));
    bh8 zz = t ^ t;
    bh8 a2 = (quad < 2) ? zz : t;                                 // [0;Qh]
    f32x4 g[8];
    #pragma unroll
    for (int ti = 0; ti < 8; ++ti) {
        const u16* brow = Qp + (ti*16 + lid)*QP_ST;
        bh8 b1 = *(const bh8*)(brow + (quad & 1)*8);              // [Qh;Qh]
        bh8 b2 = *(const bh8*)(brow + quad*8);                    // [Qh;Ql]
        f32x4 acc = {0.f,0.f,0.f,0.f};
        acc = MFMA16(a1, b1, acc);
        acc = MFMA16(a2, b2, acc);
        g[ti] = acc;
    }
    float inv[4];
    #pragma unroll
    for (int r = 0; r < 4; ++r) {
        float s = 0.f;
        #pragma unroll
        for (int ti = 0; ti < 8; ++ti) {
            const float p = fexp2(g[ti][r]);
            g[ti][r] = p; s += p;
        }
        s += __shfl_xor(s, 1); s += __shfl_xor(s, 2);
        s += __shfl_xor(s, 4); s += __shfl_xor(s, 8);
        inv[r] = frcp(s);
    }
    const int X  = 2*(lid & 7);               // row-dependent unit swizzle
    const int uc = ((4*w + quad) ^ X) << 2;   // u16 offset of this lane's 8B unit
    #pragma unroll
    for (int ti = 0; ti < 8; ++ti) {
        uint2 dv;
        dv.x = cvtpk_rn(g[ti][0]*inv[0], g[ti][1]*inv[1]);
        dv.y = cvtpk_rn(g[ti][2]*inv[2], g[ti][3]*inv[3]);
        *(uint2*)(PT + (ti*16 + lid)*PT_ST + uc) = dv;
    }
}

// PV for t-chunk [32w,+32), K=64 (s-half h), accumulating into c0,c1.
// P^T read: 16B = unit pair {(8ks+2quad)^X, +1} (X even -> adjacent & aligned).
__device__ __forceinline__ void pv_ctx(const u16* PT, const u16* Vh, int h,
                                       f32x4& c0, f32x4& c1, int w, int lid, int quad)
{
    const int X = 2*(lid & 7);
    #pragma unroll
    for (int tj2 = 0; tj2 < 2; ++tj2) {
        const int tj = 2*w + tj2;
        f32x4 acc = tj2 ? c1 : c0;
        #pragma unroll
        for (int ks = 0; ks < 2; ++ks) {
            bh8 pa = *(const bh8*)(PT + (tj*16 + lid)*PT_ST + (((8*ks + 2*quad) ^ X) << 2));
            bh8 vb = *(const bh8*)(Vh + lid*VH_ST + h*64 + ks*32 + quad*8);
            acc = MFMA16(pa, vb, acc);
        }
        if (tj2) c1 = acc; else c0 = acc;
    }
}

__global__ __launch_bounds__(256, 4)
void axial_attn_mfma(const float* __restrict__ z, const u16* __restrict__ wsu,
                     float* __restrict__ out)
{
    __shared__ __align__(16) unsigned char lds[LDS_TOT];
    u16* const ptAh = (u16*)(lds + OFF_AH);
    u16* const ptAl = (u16*)(lds + OFF_AL);
    u16* const ptPT = (u16*)(lds + OFF_PT);
    u16* const ptVI = (u16*)(lds + OFF_VIN);
    u16* const ptQP = (u16*)(lds + OFF_QP);
    u16* const ptVH = (u16*)(lds + OFF_VH);

    const int tid = threadIdx.x;
    const int w = tid >> 6, lane = tid & 63, quad = lane >> 4, lid = lane & 15;

    // XCD-aware swizzle: same-XCD blocks cover contiguous xi
    const int blk = blockIdx.x;
    const int j   = blk >> 3;
    const int xi  = ((blk & 7) << 4) | (j & 15);
    const int q   = (j >> 4) & 3;
    const int bi  = j >> 6;
    const int N   = (((bi << 7) | xi) << 2) | q;
    const size_t zbase = (size_t)bi << 20;

    const int c8 = tid >> 5, l5 = tid & 31;        // ch-octet, A-row
    const int vl0 = tid >> 4, vc0 = (tid & 15) << 2;
    const int miQ = w >> 1, niA = (w & 1) * 2;

    // ---- register prefetch of ALL z reads (thread owns 8 consecutive ch) ----
    float a1r[8], a2r[8];
    float4 v4[2];
    {
        const float* s1 = z + zbase + ((size_t)xi << 7) + (q << 5) + l5;
        const float* s2 = z + zbase + (((size_t)(q*32 + l5)) << 7) + xi;
        #pragma unroll
        for (int k = 0; k < 8; ++k)
            a1r[k] = s1[(size_t)(c8*8 + k) << 14];
        const float4* sv = (const float4*)(z + ((size_t)N << 11));
        v4[0] = sv[tid]; v4[1] = sv[tid + 256];
        #pragma unroll
        for (int k = 0; k < 8; ++k)
            a2r[k] = s2[(size_t)(c8*8 + k) << 14];
    }

    // ---- stage A1 (hi/lo, single b128 each) + Vin (RN pair-pack) ----
    {
        u32 hp[4], lp[4];
        #pragma unroll
        for (int k = 0; k < 4; ++k) splitpk(a1r[2*k], a1r[2*k+1], hp[k], lp[k]);
        *(uint4*)(ptAh + l5*AIMG_ST + c8*8) = make_uint4(hp[0], hp[1], hp[2], hp[3]);
        *(uint4*)(ptAl + l5*AIMG_ST + c8*8) = make_uint4(lp[0], lp[1], lp[2], lp[3]);
    }
    #pragma unroll
    for (int k = 0; k < 2; ++k) {
        const float4 vv = v4[k];
        uint2 dv;
        dv.x = cvtpk_rn(vv.x, vv.y);
        dv.y = cvtpk_rn(vv.z, vv.w);
        *(uint2*)(ptVI + (vl0 + 16*k)*AIMG_ST + vc0) = dv;
    }
    __syncthreads();                                            // S1

    gemm_q(ptAh, ptAl, wsu, ptQP, miQ, niA, lid, quad);         // Q1
    gemm_v(ptVI, wsu, ptVH, miQ, niA, lid, quad);               // V
    __syncthreads();                                            // S2

    f32x4 c10 = {0.f,0.f,0.f,0.f}, c11 = {0.f,0.f,0.f,0.f};
    gram_pt(ptQP, ptPT, 0, w, lid, quad);                       // branch-1 s-half 0
    __syncthreads();                                            // S3
    pv_ctx(ptPT, ptVH, 0, c10, c11, w, lid, quad);
    __syncthreads();                                            // S4 (WAR on PT)
    gram_pt(ptQP, ptPT, 1, w, lid, quad);                       // branch-1 s-half 1
    __syncthreads();                                            // S5
    pv_ctx(ptPT, ptVH, 1, c10, c11, w, lid, quad);
    __syncthreads();                                            // S6 (PT reads done)

    // ---- stage A2 (hi/lo, b128) into PT region ----
    {
        u32 hp[4], lp[4];
        #pragma unroll
        for (int k = 0; k < 4; ++k) splitpk(a2r[2*k], a2r[2*k+1], hp[k], lp[k]);
        *(uint4*)(ptAh + l5*AIMG_ST + c8*8) = make_uint4(hp[0], hp[1], hp[2], hp[3]);
        *(uint4*)(ptAl + l5*AIMG_ST + c8*8) = make_uint4(lp[0], lp[1], lp[2], lp[3]);
    }
    __syncthreads();                                            // S7

    gemm_q(ptAh, ptAl, wsu, ptQP, miQ, niA, lid, quad);         // Q2
    __syncthreads();                                            // S8

    f32x4 c20 = {0.f,0.f,0.f,0.f}, c21 = {0.f,0.f,0.f,0.f};
    gram_pt(ptQP, ptPT, 0, w, lid, quad);                       // branch-2 s-half 0
    __syncthreads();                                            // S9
    pv_ctx(ptPT, ptVH, 0, c20, c21, w, lid, quad);
    __syncthreads();                                            // S10 (WAR on PT)
    gram_pt(ptQP, ptPT, 1, w, lid, quad);                       // branch-2 s-half 1
    __syncthreads();                                            // S11
    pv_ctx(ptPT, ptVH, 1, c20, c21, w, lid, quad);

    // ---- epilogue: out[d=lid][t] = lrelu(ctx1)+lrelu(ctx2), float4 over r ----
    float* ob = out + ((size_t)N << 11) + lid*128;
    #pragma unroll
    for (int tj2 = 0; tj2 < 2; ++tj2) {
        f32x4 a = tj2 ? c11 : c10;
        f32x4 b = tj2 ? c21 : c20;
        float4 ov;
        ov.x = lrelu(a[0]) + lrelu(b[0]);
        ov.y = lrelu(a[1]) + lrelu(b[1]);
        ov.z = lrelu(a[2]) + lrelu(b[2]);
        ov.w = lrelu(a[3]) + lrelu(b[3]);
        *(float4*)(ob + (2*w + tj2)*16 + quad*4) = ov;
    }
}

extern "C" void kernel_launch(void* const* d_in, const int* in_sizes, int n_in,
                              void* d_out, int out_size, void* d_ws, size_t ws_size,
                              hipStream_t stream) {
    const float* z  = (const float*)d_in[0];
    const float* Wq = (const float*)d_in[1];
    const float* Wk = (const float*)d_in[2];
    float* out = (float*)d_out;
    u16* ws = (u16*)d_ws;
    hipLaunchKernelGGL(split_w_kernel, dim3(32), dim3(256), 0, stream, Wq, Wk, ws);
    hipLaunchKernelGGL(axial_attn_mfma, dim3(4096), dim3(256), 0, stream, z, ws, out);
}